// Round 5
// baseline (1046.877 us; speedup 1.0000x reference)
//
#include <hip/hip_runtime.h>

// ---------------------------------------------------------------------------
// ContrastiveLoss: loss = mean_i [ 0.5*(LSE_row_i + LSE_col_i) - diag_i ]
// over logits = normalize(img) @ normalize(txt)^T / 0.07, N=8192, D=1024.
// |logit| <= 14.29 -> exp() safe in fp32, no max subtraction needed.
//
// R19 = R17 geometry (256x256 tile, 4 waves of 128x128, 1 wave/SIMD,
// 512-reg budget, dbuf 128KB LDS) with a ROLLED schedule (4 iters x 2 tiles)
// -- R17/R18's fully-peeled 512-MFMA body is the prime suspect for the two
// container failures (register-allocation blowup at ~470 live regs), so the
// schedule is re-expressed compile-light: 128 MFMAs in the loop body.
// Stall model (R14/R15/R16 all ~28% MfmaUtil = MFMA-floor/dur): reads that
// feed the SAME tile's MFMAs serialize read-phase and MFMA-phase across the
// barrier-locked waves (m233's 72%-stall signature). Fix: af frag dbuf --
// no ds_read in iter t feeds iter t's MFMAs except bg, which is consumed
// tn-outer (supply 96cy/bg vs demand 276cy/bg -> only bg[0] lead-in exposed).
// Per tile:
//   vmcnt(8)                 // retires B(t),A(t+1) (issued >=1 tile ago)
//   bar                      // publish
//   bg(t) <- Bs[cur]; af(t+1) <- As[nxt]   // 32 ds_reads
//   stageA(t+2) -> As[cur]   // safe: As[cur] last read iter t-1, barrier'd
//   MFMA 8x8 tn-outer        // af in regs, bg pipelined
//   lgkm0; bar               // ALL waves' reads of Bs[cur]/As[nxt] drained
//   stageB(t+2) -> Bs[cur]   // WAR-provably-safe B overwrite
// vmcnt ledger: steady outstanding [B(t),A(t+1),B(t+1)]=24 -> vmcnt(8)
// retires 16 oldest exactly; vmcnt(0) at t=7 only. Prologue A0,B0,A1,B1 ->
// vmcnt(24) retires A0 for the af(0) pre-read.
// Carried: R7/R10 producer chunk-interleave -> 0-conflict b128 LDS reads
// (slot = quad ^ ((row>>1)&3)); R13 inverted XCD swizzle; R4/R1 swizzle
// identities ((row>>1)&3 invariant under +64j rows).
// ---------------------------------------------------------------------------

#define BM 256
#define BN 256
#define BKB 128   // fp8 K-bytes per iteration (one MFMA k-step)

typedef float floatx4 __attribute__((ext_vector_type(4)));
typedef int   intx4   __attribute__((ext_vector_type(4)));
typedef int   intx8   __attribute__((ext_vector_type(8)));

__device__ __forceinline__ void gload_lds16(const unsigned char* g, unsigned char* lds) {
    __builtin_amdgcn_global_load_lds(
        (const __attribute__((address_space(1))) void*)g,
        (__attribute__((address_space(3))) void*)lds,
        16, 0, 0);
}

// ---- Kernel 1: row L2-normalize, x16, fp32 -> fp8 e4m3, chunk-interleaved --
__global__ __launch_bounds__(256)
void normalize_fp8(const float* __restrict__ img, const float* __restrict__ txt,
                   unsigned int* __restrict__ oimg, unsigned int* __restrict__ otxt,
                   float* __restrict__ sums, float* __restrict__ out, int N) {
    const int gi = blockIdx.x * 256 + threadIdx.x;
    if (gi < 2 * N) sums[gi] = 0.f;
    if (gi == 0) out[0] = 0.f;

    const int gw = blockIdx.x * 4 + (threadIdx.x >> 6);   // row id in [0,2N)
    const int lane = threadIdx.x & 63;
    const float* in = (gw < N) ? img : txt;
    unsigned int* o = (gw < N) ? oimg : otxt;
    const int row = (gw < N) ? gw : gw - N;
    const float4* rp = (const float4*)(in + (size_t)row * 1024);

    float4 v[4];
    float ss = 0.f;
    #pragma unroll
    for (int j = 0; j < 4; ++j) {
        v[j] = rp[j * 64 + lane];
        ss += v[j].x * v[j].x + v[j].y * v[j].y + v[j].z * v[j].z + v[j].w * v[j].w;
    }
    #pragma unroll
    for (int o2 = 1; o2 < 64; o2 <<= 1) ss += __shfl_xor(ss, o2);
    const float inv = 16.0f / fmaxf(sqrtf(ss), 1e-8f);   // x16 quantization scale
    #pragma unroll
    for (int j = 0; j < 4; ++j) {
        int p = __builtin_amdgcn_cvt_pk_fp8_f32(v[j].x * inv, v[j].y * inv, 0, false);
        p = __builtin_amdgcn_cvt_pk_fp8_f32(v[j].z * inv, v[j].w * inv, p, true);
        const int d = j * 64 + lane;
        const int c = (d >> 2) & 7;
        const int pp = (c & 1) * 4 + (c >> 1);
        const int dp = (d & ~31) | (pp * 4 + (d & 3));
        o[(size_t)row * 256 + dp] = (unsigned int)p;
    }
}

#define MF(a, b, c) __builtin_amdgcn_mfma_scale_f32_16x16x128_f8f6f4( \
        (a), (b), (c), 0, 0, 0, 127, 0, 127)

// One K-tile. CUR/NXT are literals; T_ may be a runtime value (wave-uniform).
#define ITER(T_, CUR, NXT) do { \
    const int t_ = (T_); \
    if (t_ < 7) { asm volatile("s_waitcnt vmcnt(8)" ::: "memory"); } \
    else        { asm volatile("s_waitcnt vmcnt(0)" ::: "memory"); } \
    __builtin_amdgcn_s_barrier(); \
    { \
        const unsigned char* Bc = Bs + (CUR) * 32768; \
        _Pragma("unroll") \
        for (int q = 0; q < 8; ++q) bg[q] = rdB(Bc, q); \
    } \
    asm volatile("" ::: "memory"); \
    if (t_ < 7) { \
        const unsigned char* An = As + (NXT) * 32768; \
        _Pragma("unroll") \
        for (int q = 0; q < 8; ++q) afr[NXT][q] = rdA(An, q); \
    } \
    if (t_ < 6) stageA((t_ + 2) * BKB, (CUR) * 32768); \
    _Pragma("unroll") \
    for (int tn = 0; tn < 8; ++tn) \
        _Pragma("unroll") \
        for (int tm = 0; tm < 8; ++tm) \
            acc[tm][tn] = MF(afr[CUR][tm], bg[tn], acc[tm][tn]); \
    asm volatile("s_waitcnt lgkmcnt(0)" ::: "memory"); \
    __builtin_amdgcn_s_barrier(); \
    if (t_ < 6) stageB((t_ + 2) * BKB, (CUR) * 32768); \
} while (0)

// ---- Kernel 2: 256x256-tile NT MX-fp8 GEMM + fused exp/row-col sums/diag ---
__global__ __launch_bounds__(256, 1)
void gemm_exp_kernel(const unsigned char* __restrict__ A,   // img_q [N][K] fp8 (interleaved)
                     const unsigned char* __restrict__ B,   // txt_q [N][K] fp8 (interleaved)
                     float* __restrict__ rowsum, float* __restrict__ colsum,
                     float* __restrict__ diag, int K, float scale) {
    // XCD-inverted swizzle: xcd = id&7 owns bm strip [xcd*4, xcd*4+4).
    const int id = blockIdx.x;
    const int idp = id >> 3;
    const int bm = (id & 7) * 4 + (idp & 3);
    const int bn = idp >> 2;

    // LDS per matrix: [buf:32768][win:16384][row:64][slot:16];
    // slot s of row r holds global chunk s ^ ((r>>1)&3) of that window.
    __shared__ unsigned char As[2 * 2 * 256 * 64];   // 64 KB
    __shared__ unsigned char Bs[2 * 2 * 256 * 64];   // 64 KB

    const int tid = threadIdx.x;
    const int lane = tid & 63;
    const int wave = tid >> 6;           // 0..3
    const int quad = lane >> 4;
    const int lanelo = lane & 15;
    const int wrow = (wave >> 1) * 128;  // output row strip
    const int wcol = (wave & 1) * 128;   // output col strip

    floatx4 acc[8][8] = {};
    intx8 afr[2][8];
    intx8 bg[8];

    // ---- staging: thread t covers chunk c = t + 256j, j=0..7, per matrix ----
    // c -> win = j>>2, row = 64*(j&3) + (t>>2), slot = t&3; LDS addr = c*16.
    const int r0 = tid >> 2;             // 0..63
    const int xa = ((tid & 3) ^ ((r0 >> 1) & 3)) * 16;  // +64j rows: invariant
    const unsigned char* pa = A + ((size_t)bm * BM + r0) * K + xa;
    const unsigned char* pb = B + ((size_t)bn * BN + r0) * K + xa;
    unsigned char* lA = As + tid * 16;
    unsigned char* lB = Bs + tid * 16;

    auto stageA = [&](int k2, int bo) {
        #pragma unroll
        for (int j = 0; j < 8; ++j) {
            const int ro = 64 * (j & 3);
            const int wo = (j >> 2) * 64;
            gload_lds16(pa + (size_t)ro * K + wo + k2, lA + bo + j * 4096);
        }
    };
    auto stageB = [&](int k2, int bo) {
        #pragma unroll
        for (int j = 0; j < 8; ++j) {
            const int ro = 64 * (j & 3);
            const int wo = (j >> 2) * 64;
            gload_lds16(pb + (size_t)ro * K + wo + k2, lB + bo + j * 4096);
        }
    };

    // ---- fragment read offsets (zero-conflict chunk-interleave geometry) ----
    const int swx = (quad ^ ((lanelo >> 1) & 3)) * 16;
    const int aoffB = (wrow + lanelo) * 64 + swx;
    const int boffB = (wcol + lanelo) * 64 + swx;

    auto rdA = [&](const unsigned char* Ab, int tm) -> intx8 {
        const intx4 lo = *(const intx4*)(Ab + aoffB + tm * 1024);
        const intx4 hi = *(const intx4*)(Ab + 16384 + aoffB + tm * 1024);
        return __builtin_shufflevector(lo, hi, 0, 1, 2, 3, 4, 5, 6, 7);
    };
    auto rdB = [&](const unsigned char* Bb, int tn) -> intx8 {
        const intx4 lo = *(const intx4*)(Bb + boffB + tn * 1024);
        const intx4 hi = *(const intx4*)(Bb + 16384 + boffB + tn * 1024);
        return __builtin_shufflevector(lo, hi, 0, 1, 2, 3, 4, 5, 6, 7);
    };

    // ---- prologue: stage tiles 0,1 (order A0,B0,A1,B1); pre-read af(0) ----
    stageA(0, 0);       stageB(0, 0);
    stageA(BKB, 32768); stageB(BKB, 32768);
    asm volatile("s_waitcnt vmcnt(24)" ::: "memory");   // A(0) landed
    __builtin_amdgcn_s_barrier();
    #pragma unroll
    for (int q = 0; q < 8; ++q) afr[0][q] = rdA(As, q);
    asm volatile("s_waitcnt lgkmcnt(0)" ::: "memory");  // af(0) in regs

    // ---- 8 K-tiles: rolled 4 x unroll-2 (buf index static per body) ----
    for (int tt = 0; tt < 4; ++tt) {
        ITER(2 * tt,     0, 1);
        ITER(2 * tt + 1, 1, 0);
    }

    // ---- epilogue: scale, capture diag, exp in place ----
    const int growb = bm * BM + wrow;
    const int gcolb = bn * BN + wcol;

    #pragma unroll
    for (int tm = 0; tm < 8; ++tm)
        #pragma unroll
        for (int tn = 0; tn < 8; ++tn)
            #pragma unroll
            for (int r = 0; r < 4; ++r) {
                const float l = acc[tm][tn][r] * scale;
                const int grow = growb + tm * 16 + quad * 4 + r;
                const int gcol = gcolb + tn * 16 + lanelo;
                if (grow == gcol) diag[grow] = l;
                acc[tm][tn][r] = __expf(l);
            }

    // ---- row sums: reduce over the 16 lanes sharing a row, then atomicAdd ----
    #pragma unroll
    for (int tm = 0; tm < 8; ++tm) {
        floatx4 rs = acc[tm][0] + acc[tm][1] + acc[tm][2] + acc[tm][3]
                   + acc[tm][4] + acc[tm][5] + acc[tm][6] + acc[tm][7];
        #pragma unroll
        for (int r = 0; r < 4; ++r) {
            float v = rs[r];
            v += __shfl_xor(v, 1);
            v += __shfl_xor(v, 2);
            v += __shfl_xor(v, 4);
            v += __shfl_xor(v, 8);
            if (lanelo == 0)
                atomicAdd(&rowsum[growb + tm * 16 + quad * 4 + r], v);
        }
    }

    // ---- col sums: reduce over quads (xor 16, 32), then atomicAdd ----
    #pragma unroll
    for (int tn = 0; tn < 8; ++tn) {
        float cs = 0.f;
        #pragma unroll
        for (int tm = 0; tm < 8; ++tm)
            cs += acc[tm][tn][0] + acc[tm][tn][1] + acc[tm][tn][2] + acc[tm][tn][3];
        cs += __shfl_xor(cs, 16);
        cs += __shfl_xor(cs, 32);
        if (quad == 0)
            atomicAdd(&colsum[gcolb + tn * 16 + lanelo], cs);
    }
}

// ---- Kernel 3: loss = mean( 0.5*(log(rowsum)+log(colsum)) - diag ) ---------
__global__ __launch_bounds__(256)
void final_reduce(const float* __restrict__ rowsum, const float* __restrict__ colsum,
                  const float* __restrict__ diag, float* __restrict__ out, int n) {
    const int i = blockIdx.x * 256 + threadIdx.x;
    const int t = threadIdx.x;
    float v = 0.5f * (logf(rowsum[i]) + logf(colsum[i])) - diag[i];
    #pragma unroll
    for (int o = 1; o < 64; o <<= 1) v += __shfl_xor(v, o);
    __shared__ float ws[4];
    if ((t & 63) == 0) ws[t >> 6] = v;
    __syncthreads();
    if (t == 0) atomicAdd(out, (ws[0] + ws[1] + ws[2] + ws[3]) / (float)n);
}

extern "C" void kernel_launch(void* const* d_in, const int* in_sizes, int n_in,
                              void* d_out, int out_size, void* d_ws, size_t ws_size,
                              hipStream_t stream) {
    const float* img = (const float*)d_in[0];
    const float* txt = (const float*)d_in[1];
    float* out = (float*)d_out;

    const int D = 1024;
    const int N = in_sizes[0] / D;   // 8192

    unsigned char* imgq = (unsigned char*)d_ws;
    unsigned char* txtq = imgq + (size_t)N * D;
    float* rowsum = (float*)(txtq + (size_t)N * D);   // rowsum[N] ++ colsum[N]
    float* colsum = rowsum + N;
    float* diag = colsum + N;

    normalize_fp8<<<2 * N / 4, 256, 0, stream>>>(img, txt, (unsigned int*)imgq,
                                                 (unsigned int*)txtq, rowsum, out, N);

    // acc = sum of (16a)(16b) = 256*cos; scale undoes 256 and applies 1/T.
    gemm_exp_kernel<<<(N / BM) * (N / BN), 256, 0, stream>>>(
        imgq, txtq, rowsum, colsum, diag, D, 1.0f / (256.0f * 0.07f));
    final_reduce<<<N / 256, 256, 0, stream>>>(rowsum, colsum, diag, out, N);
}

// Round 6
// 260.402 us; speedup vs baseline: 4.0202x; 4.0202x over previous
//
#include <hip/hip_runtime.h>

// ---------------------------------------------------------------------------
// ContrastiveLoss: loss = mean_i [ 0.5*(LSE_row_i + LSE_col_i) - diag_i ]
// over logits = normalize(img) @ normalize(txt)^T / 0.07, N=8192, D=1024.
// |logit| <= 14.29 -> exp() safe in fp32, no max subtraction needed.
//
// R20 = R19 geometry (256x256, 4 waves of 128x128, 1 wave/SIMD, dbuf 128KB
// LDS) with the register budget FIXED. R19 spilled (VGPR=256, FETCH 1.85GB
// of scratch traffic, 930us): acc 256 + af-dbuf 128 + bg 64 + addr ~= 490
// live regs. R20 trims the frag live-set to ~150 ArchVGPR:
//   - NO cross-tile af dbuf. Per tile: read bg[0..7] + af pair0 at tile
//     start (lead-in ~250cy exposed vs 2200cy MFMA floor), then 4 bursts of
//     {2 tm x 8 tn MFMA} with af pair p+1 rolling-prefetched inside burst p
//     (af live = 2 pairs = 32 regs; bg = 64; acc 256 -> AGPR).
//   - ALL staging (A and B, 16 gloads) issued after bar2 (reads-drained
//     barrier) -> WAR-clean overwrite of buf[cur] for tile t+2.
// Why this geometry: LDS traffic per block-tile at 256^2/4-wave = 192KB
// (1714 CU-cy at 112 B/cy) < MFMA floor 2200 cy -> MFMA-bound. At 128^2
// (R14) it's 96KB = 857 cy vs 550 cy MFMA -> structurally LDS-bound (64%
// util cap even perfectly scheduled). 8-wave 256^2 = 256KB = LDS-bound too.
// vmcnt ledger (8 gloads per stage call, A+B = 16/tile): tile t issues
// A(t+2)+B(t+2) at its end; at tile t start outstanding = A(t+1),B(t+1)=16
// -> vmcnt(16) waits only if A(t),B(t) (issued a full tile ago) unretired
// (~never). vmcnt(0) only at t=7. Prologue A0,B0,A1,B1 = 32 out; tile 0's
// vmcnt(16) retires exactly A0,B0. setprio dropped (1 wave/SIMD).
// Carried: R7/R10 producer chunk-interleave -> 0-conflict b128 LDS reads
// (slot = quad ^ ((row>>1)&3)); R13 inverted XCD swizzle; R4/R1 swizzle
// identities ((row>>1)&3 invariant under +16/+64/+128 rows).
// ---------------------------------------------------------------------------

#define BM 256
#define BN 256
#define BKB 128   // fp8 K-bytes per iteration (one MFMA k-step)

typedef float floatx4 __attribute__((ext_vector_type(4)));
typedef int   intx4   __attribute__((ext_vector_type(4)));
typedef int   intx8   __attribute__((ext_vector_type(8)));

__device__ __forceinline__ void gload_lds16(const unsigned char* g, unsigned char* lds) {
    __builtin_amdgcn_global_load_lds(
        (const __attribute__((address_space(1))) void*)g,
        (__attribute__((address_space(3))) void*)lds,
        16, 0, 0);
}

// ---- Kernel 1: row L2-normalize, x16, fp32 -> fp8 e4m3, chunk-interleaved --
__global__ __launch_bounds__(256)
void normalize_fp8(const float* __restrict__ img, const float* __restrict__ txt,
                   unsigned int* __restrict__ oimg, unsigned int* __restrict__ otxt,
                   float* __restrict__ sums, float* __restrict__ out, int N) {
    const int gi = blockIdx.x * 256 + threadIdx.x;
    if (gi < 2 * N) sums[gi] = 0.f;
    if (gi == 0) out[0] = 0.f;

    const int gw = blockIdx.x * 4 + (threadIdx.x >> 6);   // row id in [0,2N)
    const int lane = threadIdx.x & 63;
    const float* in = (gw < N) ? img : txt;
    unsigned int* o = (gw < N) ? oimg : otxt;
    const int row = (gw < N) ? gw : gw - N;
    const float4* rp = (const float4*)(in + (size_t)row * 1024);

    float4 v[4];
    float ss = 0.f;
    #pragma unroll
    for (int j = 0; j < 4; ++j) {
        v[j] = rp[j * 64 + lane];
        ss += v[j].x * v[j].x + v[j].y * v[j].y + v[j].z * v[j].z + v[j].w * v[j].w;
    }
    #pragma unroll
    for (int o2 = 1; o2 < 64; o2 <<= 1) ss += __shfl_xor(ss, o2);
    const float inv = 16.0f / fmaxf(sqrtf(ss), 1e-8f);   // x16 quantization scale
    #pragma unroll
    for (int j = 0; j < 4; ++j) {
        int p = __builtin_amdgcn_cvt_pk_fp8_f32(v[j].x * inv, v[j].y * inv, 0, false);
        p = __builtin_amdgcn_cvt_pk_fp8_f32(v[j].z * inv, v[j].w * inv, p, true);
        const int d = j * 64 + lane;
        const int c = (d >> 2) & 7;
        const int pp = (c & 1) * 4 + (c >> 1);
        const int dp = (d & ~31) | (pp * 4 + (d & 3));
        o[(size_t)row * 256 + dp] = (unsigned int)p;
    }
}

#define MF(a, b, c) __builtin_amdgcn_mfma_scale_f32_16x16x128_f8f6f4( \
        (a), (b), (c), 0, 0, 0, 127, 0, 127)

// One K-tile. CUR is a literal at every expansion; T_ wave-uniform runtime.
#define ITER(T_, CUR) do { \
    const int t_ = (T_); \
    if (t_ < 7) { asm volatile("s_waitcnt vmcnt(16)" ::: "memory"); } \
    else        { asm volatile("s_waitcnt vmcnt(0)" ::: "memory"); } \
    __builtin_amdgcn_s_barrier(); \
    const unsigned char* Ac = As + (CUR) * 32768; \
    const unsigned char* Bc = Bs + (CUR) * 32768; \
    _Pragma("unroll") \
    for (int q = 0; q < 8; ++q) bg[q] = rdB(Bc, q); \
    af[0][0] = rdA(Ac, 0); af[0][1] = rdA(Ac, 1); \
    _Pragma("unroll") \
    for (int p = 0; p < 4; ++p) { \
        if (p < 3) { \
            af[(p + 1) & 1][0] = rdA(Ac, 2 * p + 2); \
            af[(p + 1) & 1][1] = rdA(Ac, 2 * p + 3); \
        } \
        _Pragma("unroll") \
        for (int u = 0; u < 2; ++u) \
            _Pragma("unroll") \
            for (int tn = 0; tn < 8; ++tn) \
                acc[2 * p + u][tn] = MF(af[p & 1][u], bg[tn], acc[2 * p + u][tn]); \
    } \
    asm volatile("s_waitcnt lgkmcnt(0)" ::: "memory"); \
    __builtin_amdgcn_s_barrier(); \
    if (t_ < 6) { stageA((t_ + 2) * BKB, (CUR) * 32768); \
                  stageB((t_ + 2) * BKB, (CUR) * 32768); } \
} while (0)

// ---- Kernel 2: 256x256-tile NT MX-fp8 GEMM + fused exp/row-col sums/diag ---
__global__ __launch_bounds__(256, 1)
void gemm_exp_kernel(const unsigned char* __restrict__ A,   // img_q [N][K] fp8 (interleaved)
                     const unsigned char* __restrict__ B,   // txt_q [N][K] fp8 (interleaved)
                     float* __restrict__ rowsum, float* __restrict__ colsum,
                     float* __restrict__ diag, int K, float scale) {
    // XCD-inverted swizzle: xcd = id&7 owns bm strip [xcd*4, xcd*4+4).
    const int id = blockIdx.x;
    const int idp = id >> 3;
    const int bm = (id & 7) * 4 + (idp & 3);
    const int bn = idp >> 2;

    // LDS per matrix: [buf:32768][win:16384][row:64][slot:16];
    // slot s of row r holds global chunk s ^ ((r>>1)&3) of that window.
    __shared__ unsigned char As[2 * 2 * 256 * 64];   // 64 KB
    __shared__ unsigned char Bs[2 * 2 * 256 * 64];   // 64 KB

    const int tid = threadIdx.x;
    const int lane = tid & 63;
    const int wave = tid >> 6;           // 0..3
    const int quad = lane >> 4;
    const int lanelo = lane & 15;
    const int wrow = (wave >> 1) * 128;  // output row strip
    const int wcol = (wave & 1) * 128;   // output col strip

    floatx4 acc[8][8] = {};
    intx8 af[2][2];
    intx8 bg[8];

    // ---- staging: thread t covers chunk c = t + 256j, j=0..7, per matrix ----
    // c -> win = j>>2, row = 64*(j&3) + (t>>2), slot = t&3; LDS addr = c*16.
    const int r0 = tid >> 2;             // 0..63
    const int xa = ((tid & 3) ^ ((r0 >> 1) & 3)) * 16;  // +64j rows: invariant
    const unsigned char* pa = A + ((size_t)bm * BM + r0) * K + xa;
    const unsigned char* pb = B + ((size_t)bn * BN + r0) * K + xa;
    unsigned char* lA = As + tid * 16;
    unsigned char* lB = Bs + tid * 16;

    auto stageA = [&](int k2, int bo) {
        #pragma unroll
        for (int j = 0; j < 8; ++j) {
            const int ro = 64 * (j & 3);
            const int wo = (j >> 2) * 64;
            gload_lds16(pa + (size_t)ro * K + wo + k2, lA + bo + j * 4096);
        }
    };
    auto stageB = [&](int k2, int bo) {
        #pragma unroll
        for (int j = 0; j < 8; ++j) {
            const int ro = 64 * (j & 3);
            const int wo = (j >> 2) * 64;
            gload_lds16(pb + (size_t)ro * K + wo + k2, lB + bo + j * 4096);
        }
    };

    // ---- fragment read offsets (zero-conflict chunk-interleave geometry) ----
    const int swx = (quad ^ ((lanelo >> 1) & 3)) * 16;
    const int aoffB = (wrow + lanelo) * 64 + swx;
    const int boffB = (wcol + lanelo) * 64 + swx;

    auto rdA = [&](const unsigned char* Ab, int tm) -> intx8 {
        const intx4 lo = *(const intx4*)(Ab + aoffB + tm * 1024);
        const intx4 hi = *(const intx4*)(Ab + 16384 + aoffB + tm * 1024);
        return __builtin_shufflevector(lo, hi, 0, 1, 2, 3, 4, 5, 6, 7);
    };
    auto rdB = [&](const unsigned char* Bb, int tn) -> intx8 {
        const intx4 lo = *(const intx4*)(Bb + boffB + tn * 1024);
        const intx4 hi = *(const intx4*)(Bb + 16384 + boffB + tn * 1024);
        return __builtin_shufflevector(lo, hi, 0, 1, 2, 3, 4, 5, 6, 7);
    };

    // ---- prologue: stage tiles 0,1 (A0,B0,A1,B1 = 32 gloads) ----
    stageA(0, 0);       stageB(0, 0);
    stageA(BKB, 32768); stageB(BKB, 32768);

    // ---- 8 K-tiles: rolled 4 x unroll-2 (buf index static per body) ----
    for (int tt = 0; tt < 4; ++tt) {
        ITER(2 * tt,     0);
        ITER(2 * tt + 1, 1);
    }

    // ---- epilogue: scale, capture diag, exp in place ----
    const int growb = bm * BM + wrow;
    const int gcolb = bn * BN + wcol;

    #pragma unroll
    for (int tm = 0; tm < 8; ++tm)
        #pragma unroll
        for (int tn = 0; tn < 8; ++tn)
            #pragma unroll
            for (int r = 0; r < 4; ++r) {
                const float l = acc[tm][tn][r] * scale;
                const int grow = growb + tm * 16 + quad * 4 + r;
                const int gcol = gcolb + tn * 16 + lanelo;
                if (grow == gcol) diag[grow] = l;
                acc[tm][tn][r] = __expf(l);
            }

    // ---- row sums: reduce over the 16 lanes sharing a row, then atomicAdd ----
    #pragma unroll
    for (int tm = 0; tm < 8; ++tm) {
        floatx4 rs = acc[tm][0] + acc[tm][1] + acc[tm][2] + acc[tm][3]
                   + acc[tm][4] + acc[tm][5] + acc[tm][6] + acc[tm][7];
        #pragma unroll
        for (int r = 0; r < 4; ++r) {
            float v = rs[r];
            v += __shfl_xor(v, 1);
            v += __shfl_xor(v, 2);
            v += __shfl_xor(v, 4);
            v += __shfl_xor(v, 8);
            if (lanelo == 0)
                atomicAdd(&rowsum[growb + tm * 16 + quad * 4 + r], v);
        }
    }

    // ---- col sums: reduce over quads (xor 16, 32), then atomicAdd ----
    #pragma unroll
    for (int tn = 0; tn < 8; ++tn) {
        float cs = 0.f;
        #pragma unroll
        for (int tm = 0; tm < 8; ++tm)
            cs += acc[tm][tn][0] + acc[tm][tn][1] + acc[tm][tn][2] + acc[tm][tn][3];
        cs += __shfl_xor(cs, 16);
        cs += __shfl_xor(cs, 32);
        if (quad == 0)
            atomicAdd(&colsum[gcolb + tn * 16 + lanelo], cs);
    }
}

// ---- Kernel 3: loss = mean( 0.5*(log(rowsum)+log(colsum)) - diag ) ---------
__global__ __launch_bounds__(256)
void final_reduce(const float* __restrict__ rowsum, const float* __restrict__ colsum,
                  const float* __restrict__ diag, float* __restrict__ out, int n) {
    const int i = blockIdx.x * 256 + threadIdx.x;
    const int t = threadIdx.x;
    float v = 0.5f * (logf(rowsum[i]) + logf(colsum[i])) - diag[i];
    #pragma unroll
    for (int o = 1; o < 64; o <<= 1) v += __shfl_xor(v, o);
    __shared__ float ws[4];
    if ((t & 63) == 0) ws[t >> 6] = v;
    __syncthreads();
    if (t == 0) atomicAdd(out, (ws[0] + ws[1] + ws[2] + ws[3]) / (float)n);
}

extern "C" void kernel_launch(void* const* d_in, const int* in_sizes, int n_in,
                              void* d_out, int out_size, void* d_ws, size_t ws_size,
                              hipStream_t stream) {
    const float* img = (const float*)d_in[0];
    const float* txt = (const float*)d_in[1];
    float* out = (float*)d_out;

    const int D = 1024;
    const int N = in_sizes[0] / D;   // 8192

    unsigned char* imgq = (unsigned char*)d_ws;
    unsigned char* txtq = imgq + (size_t)N * D;
    float* rowsum = (float*)(txtq + (size_t)N * D);   // rowsum[N] ++ colsum[N]
    float* colsum = rowsum + N;
    float* diag = colsum + N;

    normalize_fp8<<<2 * N / 4, 256, 0, stream>>>(img, txt, (unsigned int*)imgq,
                                                 (unsigned int*)txtq, rowsum, out, N);

    // acc = sum of (16a)(16b) = 256*cos; scale undoes 256 and applies 1/T.
    gemm_exp_kernel<<<(N / BM) * (N / BN), 256, 0, stream>>>(
        imgq, txtq, rowsum, colsum, diag, D, 1.0f / (256.0f * 0.07f));
    final_reduce<<<N / 256, 256, 0, stream>>>(rowsum, colsum, diag, out, N);
}